// Round 1
// baseline (31.693 us; speedup 1.0000x reference)
//
#include <hip/hip_runtime.h>

#define NUM_CLASSES 6625
#define FEAT_DIM 96
#define NROWS 4096
#define CLAMP_MIN 1e-12
#define CLAMP_MAX 1e12

// One block per row: vectorized argmax over 6625 logits (first-max tie-break),
// then fused f64 squared distance ||feat_row - center_label||^2, clamped,
// stored as double to workspace.
__global__ __launch_bounds__(256) void argmax_dist_kernel(
    const float* __restrict__ pred,
    const float* __restrict__ feats,
    const float* __restrict__ centers,
    double* __restrict__ dists)
{
    const int C = NUM_CLASSES;
    const int row = blockIdx.x;
    const int tid = threadIdx.x;
    const float* p = pred + (size_t)row * C;

    float best = -__builtin_inff();
    int bidx = C;  // sentinel larger than any real index

    // Row base element offset is row*6625 ≡ row (mod 4). Scalar prefix to reach
    // 16B alignment for float4 loads.
    const int prefix = (4 - (row & 3)) & 3;
    if (tid < prefix) {
        float v = p[tid];
        if (v > best) { best = v; bidx = tid; }
    }

    const int nvec = (C - prefix) >> 2;
    const float4* pv = (const float4*)(p + prefix);
    // Per-thread indices increase monotonically, so strict '>' keeps the
    // first occurrence of the max within a thread (matches jnp.argmax).
    for (int i = tid; i < nvec; i += 256) {
        float4 v = pv[i];
        const int c0 = prefix + 4 * i;
        if (v.x > best) { best = v.x; bidx = c0; }
        if (v.y > best) { best = v.y; bidx = c0 + 1; }
        if (v.z > best) { best = v.z; bidx = c0 + 2; }
        if (v.w > best) { best = v.w; bidx = c0 + 3; }
    }

    const int tailstart = prefix + 4 * nvec;
    const int tails = C - tailstart;  // 0..3
    if (tid < tails) {
        const int c = tailstart + tid;
        float v = p[c];
        if (v > best) { best = v; bidx = c; }  // c > any earlier index this thread saw
    }

    // Block reduce (max value, min index on tie).
    __shared__ float sval[256];
    __shared__ int   sidx[256];
    sval[tid] = best;
    sidx[tid] = bidx;
    __syncthreads();
    for (int s = 128; s > 0; s >>= 1) {
        if (tid < s) {
            float v2 = sval[tid + s];
            int   i2 = sidx[tid + s];
            if (v2 > sval[tid] || (v2 == sval[tid] && i2 < sidx[tid])) {
                sval[tid] = v2;
                sidx[tid] = i2;
            }
        }
        __syncthreads();
    }
    const int label = sidx[0];  // valid: loop's last iteration ended with __syncthreads()

    // Fused f64 squared distance for this row.
    __shared__ double sd[256];
    double term = 0.0;
    if (tid < FEAT_DIM) {
        double diff = (double)feats[row * FEAT_DIM + tid]
                    - (double)centers[(size_t)label * FEAT_DIM + tid];
        term = diff * diff;
    }
    sd[tid] = term;
    __syncthreads();
    for (int s = 128; s > 0; s >>= 1) {
        if (tid < s) sd[tid] += sd[tid + s];
        __syncthreads();
    }
    if (tid == 0) {
        double dn = sd[0];
        dn = dn < CLAMP_MIN ? CLAMP_MIN : (dn > CLAMP_MAX ? CLAMP_MAX : dn);
        dists[row] = dn;
    }
}

// Single-block final reduction: mean over rows + the (C-1)*1e-12 constant that
// the reference's clip-after-mask contributes from the zeroed columns.
__global__ __launch_bounds__(256) void reduce_kernel(
    const double* __restrict__ dists, float* __restrict__ out)
{
    const int tid = threadIdx.x;
    double s = 0.0;
    for (int i = tid; i < NROWS; i += 256) s += dists[i];
    __shared__ double sd[256];
    sd[tid] = s;
    __syncthreads();
    for (int k = 128; k > 0; k >>= 1) {
        if (tid < k) sd[tid] += sd[tid + k];
        __syncthreads();
    }
    if (tid == 0) {
        out[0] = (float)(sd[0] / (double)NROWS
                         + (double)(NUM_CLASSES - 1) * CLAMP_MIN);
    }
}

extern "C" void kernel_launch(void* const* d_in, const int* in_sizes, int n_in,
                              void* d_out, int out_size, void* d_ws, size_t ws_size,
                              hipStream_t stream) {
    const float* feats   = (const float*)d_in[0];  // [4096, 96]
    const float* pred    = (const float*)d_in[1];  // [4096, 6625]
    const float* centers = (const float*)d_in[2];  // [6625, 96]
    double* dists = (double*)d_ws;                 // 4096 * 8 B = 32 KiB
    float* out = (float*)d_out;

    argmax_dist_kernel<<<NROWS, 256, 0, stream>>>(pred, feats, centers, dists);
    reduce_kernel<<<1, 256, 0, stream>>>(dists, out);
}

// Round 2
// 26.188 us; speedup vs baseline: 1.2102x; 1.2102x over previous
//
#include <hip/hip_runtime.h>

#define NUM_CLASSES 6625
#define FEAT_DIM 96
#define NROWS 4096
#define CLAMP_MIN 1e-12
#define CLAMP_MAX 1e12

// One 256-thread block per row. Vectorized argmax over 6625 logits with
// 4 independent compare chains per thread (load ILP), wave-shuffle reduce,
// then wave 0 computes the fused f64 squared distance to centers[label].
__global__ __launch_bounds__(256) void argmax_dist_kernel(
    const float* __restrict__ pred,
    const float* __restrict__ feats,
    const float* __restrict__ centers,
    double* __restrict__ dists)
{
    const int C = NUM_CLASSES;
    const int row = blockIdx.x;
    const int tid = threadIdx.x;
    const float* p = pred + (size_t)row * C;

    // Row base element offset is row*6625 ≡ row (mod 4). Scalar prefix to
    // reach 16B alignment for float4 loads.
    const int prefix = (4 - (row & 3)) & 3;

    // 4 independent chains. Within a chain indices increase monotonically, so
    // strict '>' keeps the first occurrence of the max (matches jnp.argmax).
    float b0 = -__builtin_inff(), b1 = b0, b2 = b0, b3 = b0;
    int j0 = C, j1 = C, j2 = C, j3 = C;

    if (tid < prefix) {        // indices 0..2, smaller than anything later
        float v = p[tid];
        if (v > b0) { b0 = v; j0 = tid; }
    }

    const int nvec = (C - prefix) >> 2;
    const float4* pv = (const float4*)(p + prefix);

    int i = tid;
    // Main pass: 4 float4 loads in flight per iteration.
    for (; i + 768 < nvec; i += 1024) {
        float4 v0 = pv[i];
        float4 v1 = pv[i + 256];
        float4 v2 = pv[i + 512];
        float4 v3 = pv[i + 768];
        int c0 = prefix + 4 * i;
        int c1 = c0 + 1024;
        int c2 = c0 + 2048;
        int c3 = c0 + 3072;
        if (v0.x > b0) { b0 = v0.x; j0 = c0; }
        if (v0.y > b0) { b0 = v0.y; j0 = c0 + 1; }
        if (v0.z > b0) { b0 = v0.z; j0 = c0 + 2; }
        if (v0.w > b0) { b0 = v0.w; j0 = c0 + 3; }
        if (v1.x > b1) { b1 = v1.x; j1 = c1; }
        if (v1.y > b1) { b1 = v1.y; j1 = c1 + 1; }
        if (v1.z > b1) { b1 = v1.z; j1 = c1 + 2; }
        if (v1.w > b1) { b1 = v1.w; j1 = c1 + 3; }
        if (v2.x > b2) { b2 = v2.x; j2 = c2; }
        if (v2.y > b2) { b2 = v2.y; j2 = c2 + 1; }
        if (v2.z > b2) { b2 = v2.z; j2 = c2 + 2; }
        if (v2.w > b2) { b2 = v2.w; j2 = c2 + 3; }
        if (v3.x > b3) { b3 = v3.x; j3 = c3; }
        if (v3.y > b3) { b3 = v3.y; j3 = c3 + 1; }
        if (v3.z > b3) { b3 = v3.z; j3 = c3 + 2; }
        if (v3.w > b3) { b3 = v3.w; j3 = c3 + 3; }
    }
    // Remainder into chain 0 (indices still monotonically increasing there).
    for (; i < nvec; i += 256) {
        float4 v = pv[i];
        int c0 = prefix + 4 * i;
        if (v.x > b0) { b0 = v.x; j0 = c0; }
        if (v.y > b0) { b0 = v.y; j0 = c0 + 1; }
        if (v.z > b0) { b0 = v.z; j0 = c0 + 2; }
        if (v.w > b0) { b0 = v.w; j0 = c0 + 3; }
    }
    // Tail (0..3 scalars), indices larger than everything in chain 0.
    const int tailstart = prefix + 4 * nvec;
    const int tails = C - tailstart;
    if (tid < tails) {
        int c = tailstart + tid;
        float v = p[c];
        if (v > b0) { b0 = v; j0 = c; }
    }

    // Merge chains (value desc, index asc on tie).
    float best = b0; int bidx = j0;
    if (b1 > best || (b1 == best && j1 < bidx)) { best = b1; bidx = j1; }
    if (b2 > best || (b2 == best && j2 < bidx)) { best = b2; bidx = j2; }
    if (b3 > best || (b3 == best && j3 < bidx)) { best = b3; bidx = j3; }

    // Wave-level reduce (64 lanes), no barrier.
    for (int off = 32; off > 0; off >>= 1) {
        float ov = __shfl_down(best, off, 64);
        int   oi = __shfl_down(bidx, off, 64);
        if (ov > best || (ov == best && oi < bidx)) { best = ov; bidx = oi; }
    }

    // Cross-wave merge: 4 partials through LDS, single barrier.
    __shared__ float swv[4];
    __shared__ int   swi[4];
    const int wave = tid >> 6;
    const int lane = tid & 63;
    if (lane == 0) { swv[wave] = best; swi[wave] = bidx; }
    __syncthreads();
    if (tid >= 64) return;

    float bv = swv[0]; int bi = swi[0];
    #pragma unroll
    for (int w = 1; w < 4; ++w) {
        float v2 = swv[w]; int i2 = swi[w];
        if (v2 > bv || (v2 == bv && i2 < bi)) { bv = v2; bi = i2; }
    }
    const int label = bi;  // all 64 lanes agree

    // f64 squared distance: lane handles element lane (and lane+64 if lane<32).
    const float* frow = feats + row * FEAT_DIM;
    const float* crow = centers + (size_t)label * FEAT_DIM;
    double acc;
    {
        double d0 = (double)frow[lane] - (double)crow[lane];
        acc = d0 * d0;
    }
    if (lane < 32) {
        double d1 = (double)frow[lane + 64] - (double)crow[lane + 64];
        acc += d1 * d1;
    }
    for (int off = 32; off > 0; off >>= 1)
        acc += __shfl_down(acc, off, 64);
    if (lane == 0) {
        double dn = acc;
        dn = dn < CLAMP_MIN ? CLAMP_MIN : (dn > CLAMP_MAX ? CLAMP_MAX : dn);
        dists[row] = dn;
    }
}

// Single-block final reduction: mean over rows + the (C-1)*1e-12 constant from
// the reference's clip-after-mask on the zeroed columns.
__global__ __launch_bounds__(256) void reduce_kernel(
    const double* __restrict__ dists, float* __restrict__ out)
{
    const int tid = threadIdx.x;
    double s = 0.0;
    #pragma unroll
    for (int i = 0; i < NROWS / 256; ++i) s += dists[tid + i * 256];
    for (int off = 32; off > 0; off >>= 1)
        s += __shfl_down(s, off, 64);
    __shared__ double sw[4];
    const int wave = tid >> 6;
    const int lane = tid & 63;
    if (lane == 0) sw[wave] = s;
    __syncthreads();
    if (tid == 0) {
        double t = sw[0] + sw[1] + sw[2] + sw[3];
        out[0] = (float)(t / (double)NROWS
                         + (double)(NUM_CLASSES - 1) * CLAMP_MIN);
    }
}

extern "C" void kernel_launch(void* const* d_in, const int* in_sizes, int n_in,
                              void* d_out, int out_size, void* d_ws, size_t ws_size,
                              hipStream_t stream) {
    const float* feats   = (const float*)d_in[0];  // [4096, 96]
    const float* pred    = (const float*)d_in[1];  // [4096, 6625]
    const float* centers = (const float*)d_in[2];  // [6625, 96]
    double* dists = (double*)d_ws;                 // 4096 * 8 B = 32 KiB
    float* out = (float*)d_out;

    argmax_dist_kernel<<<NROWS, 256, 0, stream>>>(pred, feats, centers, dists);
    reduce_kernel<<<1, 256, 0, stream>>>(dists, out);
}